// Round 3
// baseline (47904.596 us; speedup 1.0000x reference)
//
#include <hip/hip_runtime.h>
#include <math.h>

#define CC 1024
#define LL 2048
#define NWG 256
#define NT 256

// ws layout (32-bit words):
// [i*32], i<256  : gbar arrival epochs (128B lines)      [memset]
// [8192]         : gbar release epoch                    [memset]
// [8256 ..)      : tick slots: 2 parities x 256 slots x 16 words (64B)
//                  slot: [0..3]=h0n, [4..7]=h1n, [8]=epoch
// [24640 ..)     : logits[2048]
// [26688 ..)     : av[1024]
#define WS_FLAGS 0
#define WS_REL 8192
#define TS_BASE 8256
#define TS_STRIDE 16
#define TS_PAR (256 * TS_STRIDE)
#define WS_LOGITS (TS_BASE + 2 * TS_PAR)
#define WS_AV (WS_LOGITS + LL)
#define WS_MEMSET_BYTES (WS_LOGITS * 4)

__device__ __forceinline__ float aload(const float* p) {
  return __hip_atomic_load(p, __ATOMIC_RELAXED, __HIP_MEMORY_SCOPE_AGENT);
}
__device__ __forceinline__ void astore(float* p, float v) {
  __hip_atomic_store(p, v, __ATOMIC_RELAXED, __HIP_MEMORY_SCOPE_AGENT);
}
__device__ __forceinline__ float sigm(float x) { return 1.0f / (1.0f + __expf(-x)); }
__device__ __forceinline__ float tanh_(float x) { return 2.0f / (1.0f + __expf(-2.0f * x)) - 1.0f; }

// dot of this lane's 16-element slice: wr[256k+4lane..+4] . hc[k]
__device__ __forceinline__ float dot16(const float* wr, const float4* hc, int lane) {
  float p = 0.f;
#pragma unroll
  for (int k = 0; k < 4; ++k) {
    float4 wv = *(const float4*)(wr + 256 * k + 4 * lane);
    p = fmaf(wv.x, hc[k].x, p);
    p = fmaf(wv.y, hc[k].y, p);
    p = fmaf(wv.z, hc[k].z, p);
    p = fmaf(wv.w, hc[k].w, p);
  }
  return p;
}

// prologue-only arrival-slot barrier (no RMW)
__device__ __forceinline__ void gbar(unsigned* ws_u, unsigned epoch) {
  __syncthreads();
  if (blockIdx.x == 0) {
    const int i = threadIdx.x;
    if (i > 0 && i < NWG) {
      unsigned* slot = ws_u + WS_FLAGS + i * 32;
      while (__hip_atomic_load(slot, __ATOMIC_RELAXED, __HIP_MEMORY_SCOPE_AGENT) < epoch) {
      }
      (void)__hip_atomic_load(slot, __ATOMIC_ACQUIRE, __HIP_MEMORY_SCOPE_AGENT);
    }
    __syncthreads();
    if (i == 0)
      __hip_atomic_store(ws_u + WS_REL, epoch, __ATOMIC_RELEASE, __HIP_MEMORY_SCOPE_AGENT);
    __syncthreads();
  } else {
    if (threadIdx.x == 0) {
      __hip_atomic_store(ws_u + WS_FLAGS + blockIdx.x * 32, epoch, __ATOMIC_RELEASE,
                         __HIP_MEMORY_SCOPE_AGENT);
      unsigned* rel = ws_u + WS_REL;
      while (__hip_atomic_load(rel, __ATOMIC_RELAXED, __HIP_MEMORY_SCOPE_AGENT) < epoch) {
      }
      (void)__hip_atomic_load(rel, __ATOMIC_ACQUIRE, __HIP_MEMORY_SCOPE_AGENT);
    }
    __syncthreads();
  }
}

__global__ __launch_bounds__(NT, 1) void decoder_kernel(
    const float* __restrict__ x, const float* __restrict__ attn_w,
    const float* __restrict__ w_ih0, const float* __restrict__ w_hh0,
    const float* __restrict__ b_ih0, const float* __restrict__ b_hh0,
    const float* __restrict__ w_ih1, const float* __restrict__ w_hh1,
    const float* __restrict__ b_ih1, const float* __restrict__ b_hh1,
    float* __restrict__ out, float* __restrict__ ws) {
  const int g = blockIdx.x;
  const int tid = threadIdx.x;
  const int lane = tid & 63;
  const int w = tid >> 6;

  unsigned* ws_u = (unsigned*)ws;

  extern __shared__ float wlds[];  // 36 rows x 1024 floats = 144KB
  __shared__ __align__(16) float h0s[CC];
  __shared__ __align__(16) float h1s[CC];
  __shared__ float st[36];
  __shared__ float cgi0[12], cbh0[12], cbh1[12], cbi1[12];
  __shared__ float red[NT];

  // ---------- P0: logits[t] = dot(w2, x[t]) for this WG's 8 timesteps ----------
  {
    const float* w2 = attn_w + CC;
#pragma unroll
    for (int s = 0; s < 2; ++s) {
      int t = 8 * g + 2 * w + s;
      const float* xr = x + (size_t)t * CC;
      float p = 0.f;
#pragma unroll
      for (int k = 0; k < 4; ++k) {
        float4 xa = *(const float4*)(xr + 256 * k + 4 * lane);
        float4 wa = *(const float4*)(w2 + 256 * k + 4 * lane);
        p = fmaf(xa.x, wa.x, p);
        p = fmaf(xa.y, wa.y, p);
        p = fmaf(xa.z, wa.z, p);
        p = fmaf(xa.w, wa.w, p);
      }
#pragma unroll
      for (int off = 32; off; off >>= 1) p += __shfl_xor(p, off, 64);
      if (lane == 0) astore(ws + WS_LOGITS + t, p);
    }
  }
  gbar(ws_u, 1);

  // ---------- P1: softmax over L, av columns [4g,4g+4) ----------
  {
    float myl[8];
#pragma unroll
    for (int s = 0; s < 8; ++s) myl[s] = aload(ws + WS_LOGITS + tid + 256 * s);
    float lm = myl[0];
#pragma unroll
    for (int s = 1; s < 8; ++s) lm = fmaxf(lm, myl[s]);
    red[tid] = lm;
    __syncthreads();
    for (int stp = 128; stp; stp >>= 1) {
      if (tid < stp) red[tid] = fmaxf(red[tid], red[tid + stp]);
      __syncthreads();
    }
    float m = red[0];
    __syncthreads();
    float myw[8];
    float ls = 0.f;
#pragma unroll
    for (int s = 0; s < 8; ++s) {
      myw[s] = __expf(myl[s] - m);
      ls += myw[s];
    }
    red[tid] = ls;
    __syncthreads();
    for (int stp = 128; stp; stp >>= 1) {
      if (tid < stp) red[tid] += red[tid + stp];
      __syncthreads();
    }
    float invZ = 1.0f / red[0];
    __syncthreads();
    float acc[4] = {0.f, 0.f, 0.f, 0.f};
#pragma unroll
    for (int s = 0; s < 8; ++s) {
      int t = tid + 256 * s;
      float4 xa = *(const float4*)(x + (size_t)t * CC + 4 * g);
      acc[0] = fmaf(myw[s], xa.x, acc[0]);
      acc[1] = fmaf(myw[s], xa.y, acc[1]);
      acc[2] = fmaf(myw[s], xa.z, acc[2]);
      acc[3] = fmaf(myw[s], xa.w, acc[3]);
    }
    for (int i = 0; i < 4; ++i) {
      red[tid] = acc[i];
      __syncthreads();
      for (int stp = 128; stp; stp >>= 1) {
        if (tid < stp) red[tid] += red[tid + stp];
        __syncthreads();
      }
      if (tid == 0) astore(ws + WS_AV + 4 * g + i, red[0] * invZ);
      __syncthreads();
    }
  }
  gbar(ws_u, 2);

  // ---------- P2: gather av; gi0 = W_ih0 . av + b_ih0 (12 rows); biases ----------
#pragma unroll
  for (int i = 0; i < 4; ++i) h0s[4 * tid + i] = aload(ws + WS_AV + 4 * tid + i);
  __syncthreads();
  {
    float4 hc[4];
#pragma unroll
    for (int k = 0; k < 4; ++k) hc[k] = *(const float4*)&h0s[256 * k + 4 * lane];
#pragma unroll
    for (int jj = 0; jj < 3; ++jj) {
      int j = 3 * w + jj;  // 12 rows: j = gate*4 + e
      int gate = j >> 2, e = j & 3;
      int row = gate * CC + 4 * g + e;
      float p = dot16(w_ih0 + (size_t)row * CC, hc, lane);
#pragma unroll
      for (int off = 32; off; off >>= 1) p += __shfl_xor(p, off, 64);
      if (lane == 0) cgi0[j] = p + b_ih0[row];
    }
  }
  if (tid < 12) {
    int gate = tid >> 2, e = tid & 3;
    int row = gate * CC + 4 * g + e;
    cbh0[tid] = b_hh0[row];
    cbh1[tid] = b_hh1[row];
    cbi1[tid] = b_ih1[row];
  }

  // ---------- fill weight LDS: rows 0-11 W_hh0, 12-23 W_hh1, 24-35 W_ih1 ----------
#pragma unroll
  for (int j = 0; j < 36; ++j) {
    int m = j / 12, jl = j % 12;
    int gate = jl >> 2, e = jl & 3;
    const float* src = (m == 0 ? w_hh0 : (m == 1 ? w_hh1 : w_ih1)) +
                       ((size_t)(gate * CC + 4 * g + e) << 10);
    *(float4*)&wlds[(j << 10) + 4 * tid] = *(const float4*)(src + 4 * tid);
  }
#pragma unroll
  for (int i = 0; i < 4; ++i) {
    h0s[4 * tid + i] = 0.f;
    h1s[4 * tid + i] = 0.f;
  }
  __syncthreads();

  // ---------- skewed recurrence: tick tau computes h0[tau] and h1[tau-1] ----------
  const int e = tid & 3;
  const int eg = 4 * g + e;
  float h0last = 0.f;

  for (int tau = 0; tau <= LL; ++tau) {
    // gather publication (epoch tau, parity tau&1): full h0[tau-1], h1[tau-2]
    if (tau > 0) {
      float* sl = ws + TS_BASE + (tau & 1) * TS_PAR + tid * TS_STRIDE;
      unsigned* ep = (unsigned*)(sl + 8);
      while (__hip_atomic_load(ep, __ATOMIC_ACQUIRE, __HIP_MEMORY_SCOPE_AGENT) <
             (unsigned)tau) {
      }
      float v0 = aload(sl + 0), v1 = aload(sl + 1), v2 = aload(sl + 2), v3 = aload(sl + 3);
      float v4 = aload(sl + 4), v5 = aload(sl + 5), v6 = aload(sl + 6), v7 = aload(sl + 7);
      h0s[4 * tid + 0] = v0;
      h0s[4 * tid + 1] = v1;
      h0s[4 * tid + 2] = v2;
      h0s[4 * tid + 3] = v3;
      h1s[4 * tid + 0] = v4;
      h1s[4 * tid + 1] = v5;
      h1s[4 * tid + 2] = v6;
      h1s[4 * tid + 3] = v7;
    }
    __syncthreads();  // (a) h replicas ready

    // 9 rows per wave: 3 of W_hh0 (x h0), 3 of W_hh1 (x h1), 3 of W_ih1 (x h0)
    {
      float4 hc0[4], hc1[4];
#pragma unroll
      for (int k = 0; k < 4; ++k) {
        hc0[k] = *(const float4*)&h0s[256 * k + 4 * lane];
        hc1[k] = *(const float4*)&h1s[256 * k + 4 * lane];
      }
      float p[9];
#pragma unroll
      for (int i = 0; i < 3; ++i) {
        p[i] = dot16(wlds + ((3 * w + i) << 10), hc0, lane);
        p[3 + i] = dot16(wlds + ((12 + 3 * w + i) << 10), hc1, lane);
        p[6 + i] = dot16(wlds + ((24 + 3 * w + i) << 10), hc0, lane);
      }
#pragma unroll
      for (int off = 32; off; off >>= 1) {
#pragma unroll
        for (int i = 0; i < 9; ++i) p[i] += __shfl_xor(p[i], off, 64);
      }
      if (lane == 0) {
#pragma unroll
        for (int i = 0; i < 3; ++i) {
          st[3 * w + i] = p[i];
          st[12 + 3 * w + i] = p[3 + i];
          st[24 + 3 * w + i] = p[6 + i];
        }
      }
    }
    __syncthreads();  // (b) st ready

    // elementwise updates (all threads compute; tid<4 publish)
    float h0prev = h0s[eg];
    float h1prev = h1s[eg];
    float r0 = sigm(cgi0[e] + st[e] + cbh0[e]);
    float z0 = sigm(cgi0[4 + e] + st[4 + e] + cbh0[4 + e]);
    float n0 = tanh_(cgi0[8 + e] + r0 * (st[8 + e] + cbh0[8 + e]));
    float h0new = (1.f - z0) * n0 + z0 * h0prev;

    float ir = st[24 + e] + cbi1[e];
    float iz = st[28 + e] + cbi1[4 + e];
    float inn = st[32 + e] + cbi1[8 + e];
    float hr = st[12 + e] + cbh1[e];
    float hz = st[16 + e] + cbh1[4 + e];
    float hn = st[20 + e] + cbh1[8 + e];
    float r1 = sigm(ir + hr);
    float z1 = sigm(iz + hz);
    float n1 = tanh_(inn + r1 * hn);
    float h1new = (1.f - z1) * n1 + z1 * h1prev;

    if (tid < 4) {
      if (tau < LL) {
        float* sl = ws + TS_BASE + ((tau + 1) & 1) * TS_PAR + g * TS_STRIDE;
        astore(sl + tid, h0new);
        astore(sl + 4 + tid, (tau > 0) ? h1new : 0.f);
      }
      if (tau > 0) out[(size_t)(tau - 1) * CC + eg] = h1new;
      if (tau == LL) {
        out[(size_t)LL * CC + eg] = h0last;        // final h0 = h0[2047]
        out[(size_t)LL * CC + CC + eg] = h1new;    // final h1 = h1[2047]
      }
    }
    if (tau == LL - 1) h0last = h0new;
    __syncthreads();  // (c) publish stores drained (vmcnt0 before barrier)
    if (tau < LL && tid == 0) {
      unsigned* ep =
          (unsigned*)(ws + TS_BASE + ((tau + 1) & 1) * TS_PAR + g * TS_STRIDE + 8);
      __hip_atomic_store(ep, (unsigned)(tau + 1), __ATOMIC_RELEASE,
                         __HIP_MEMORY_SCOPE_AGENT);
    }
  }
}

extern "C" void kernel_launch(void* const* d_in, const int* in_sizes, int n_in,
                              void* d_out, int out_size, void* d_ws, size_t ws_size,
                              hipStream_t stream) {
  const float* x = (const float*)d_in[0];
  const float* attn_w = (const float*)d_in[1];
  const float* w_ih0 = (const float*)d_in[3];
  const float* w_hh0 = (const float*)d_in[4];
  const float* b_ih0 = (const float*)d_in[5];
  const float* b_hh0 = (const float*)d_in[6];
  const float* w_ih1 = (const float*)d_in[7];
  const float* w_hh1 = (const float*)d_in[8];
  const float* b_ih1 = (const float*)d_in[9];
  const float* b_hh1 = (const float*)d_in[10];
  float* out = (float*)d_out;
  float* ws = (float*)d_ws;

  static int attr_set = 0;
  if (!attr_set) {
    hipFuncSetAttribute((const void*)decoder_kernel,
                        hipFuncAttributeMaxDynamicSharedMemorySize, 36 * 1024 * 4);
    attr_set = 1;
  }

  // zero gbar flags + tick-slot epochs every call
  hipMemsetAsync(d_ws, 0, WS_MEMSET_BYTES, stream);

  void* args[] = {&x,     &attn_w, &w_ih0, &w_hh0, &b_ih0, &b_hh0,
                  &w_ih1, &w_hh1,  &b_ih1, &b_hh1, &out,   &ws};
  hipLaunchCooperativeKernel((void*)decoder_kernel, dim3(NWG), dim3(NT), args,
                             36 * 1024 * 4, stream);
}

// Round 4
// 9965.794 us; speedup vs baseline: 4.8069x; 4.8069x over previous
//
#include <hip/hip_runtime.h>
#include <math.h>

#define CC 1024
#define LL 2048
#define NWG 256
#define NT 256

typedef float f4 __attribute__((ext_vector_type(4)));
typedef unsigned u4 __attribute__((ext_vector_type(4)));

// ws word layout:
// [0..8191]      gbar arrival epochs (256 x 32 words, 128B lines)  [memset]
// [8192]         gbar release epoch                                [memset]
// [8256..8511]   ep[256] dense tick epochs (8 lines)               [memset]
// [8704..10751]  parity-0 block: h0[1024] then h1[1024]
// [10752..12799] parity-1 block: h0[1024] then h1[1024]
// [12800..14847] logits[2048]
// [14848..15871] av[1024]
#define WS_FLAGS 0
#define WS_REL 8192
#define WS_EP 8256
#define WS_PAR0 8704
#define WS_PAR1 10752
#define WS_LOGITS 12800
#define WS_AV 14848
#define WS_MEMSET_BYTES (8512 * 4)

__device__ __forceinline__ float aload(const float* p) {
  return __hip_atomic_load(p, __ATOMIC_RELAXED, __HIP_MEMORY_SCOPE_AGENT);
}
__device__ __forceinline__ void astore(float* p, float v) {
  __hip_atomic_store(p, v, __ATOMIC_RELAXED, __HIP_MEMORY_SCOPE_AGENT);
}
__device__ __forceinline__ float sigm(float x) { return 1.0f / (1.0f + __expf(-x)); }
__device__ __forceinline__ float tanh_(float x) { return 2.0f / (1.0f + __expf(-2.0f * x)) - 1.0f; }

// L1/L2-bypass 16B ops (read/write at the L3 coherence point)
__device__ __forceinline__ u4 ld16u(const unsigned* p) {
  u4 r;
  asm volatile("global_load_dwordx4 %0, %1, off sc0 sc1\n\ts_waitcnt vmcnt(0)"
               : "=v"(r)
               : "v"(p)
               : "memory");
  return r;
}
__device__ __forceinline__ void ld16x2(const float* p0, const float* p1, f4& a, f4& b) {
  asm volatile(
      "global_load_dwordx4 %0, %2, off sc0 sc1\n\t"
      "global_load_dwordx4 %1, %3, off sc0 sc1\n\t"
      "s_waitcnt vmcnt(0)"
      : "=v"(a), "=v"(b)
      : "v"(p0), "v"(p1)
      : "memory");
}
__device__ __forceinline__ void st16(float* p, f4 v) {
  asm volatile("global_store_dwordx4 %0, %1, off sc0 sc1" ::"v"(p), "v"(v) : "memory");
}

__device__ __forceinline__ float dot4(f4 a, f4 b) {
  return fmaf(a.x, b.x, fmaf(a.y, b.y, fmaf(a.z, b.z, a.w * b.w)));
}

// prologue-only arrival-slot barrier (relaxed spins + one acquire)
__device__ __forceinline__ void gbar(unsigned* ws_u, unsigned epoch) {
  __syncthreads();
  if (blockIdx.x == 0) {
    const int i = threadIdx.x;
    if (i > 0 && i < NWG) {
      unsigned* slot = ws_u + WS_FLAGS + i * 32;
      while (__hip_atomic_load(slot, __ATOMIC_RELAXED, __HIP_MEMORY_SCOPE_AGENT) < epoch) {
      }
      (void)__hip_atomic_load(slot, __ATOMIC_ACQUIRE, __HIP_MEMORY_SCOPE_AGENT);
    }
    __syncthreads();
    if (i == 0)
      __hip_atomic_store(ws_u + WS_REL, epoch, __ATOMIC_RELEASE, __HIP_MEMORY_SCOPE_AGENT);
    __syncthreads();
  } else {
    if (threadIdx.x == 0) {
      __hip_atomic_store(ws_u + WS_FLAGS + blockIdx.x * 32, epoch, __ATOMIC_RELEASE,
                         __HIP_MEMORY_SCOPE_AGENT);
      unsigned* rel = ws_u + WS_REL;
      while (__hip_atomic_load(rel, __ATOMIC_RELAXED, __HIP_MEMORY_SCOPE_AGENT) < epoch) {
      }
      (void)__hip_atomic_load(rel, __ATOMIC_ACQUIRE, __HIP_MEMORY_SCOPE_AGENT);
    }
    __syncthreads();
  }
}

#define PIN9(b)                                                                       \
  asm volatile("" : "+v"(W[b + 0]), "+v"(W[b + 1]), "+v"(W[b + 2]), "+v"(W[b + 3]),   \
                    "+v"(W[b + 4]), "+v"(W[b + 5]), "+v"(W[b + 6]), "+v"(W[b + 7]),   \
                    "+v"(W[b + 8]))

__global__ __launch_bounds__(NT, 1) void decoder_kernel(
    const float* __restrict__ x, const float* __restrict__ attn_w,
    const float* __restrict__ w_ih0, const float* __restrict__ w_hh0,
    const float* __restrict__ b_ih0, const float* __restrict__ b_hh0,
    const float* __restrict__ w_ih1, const float* __restrict__ w_hh1,
    const float* __restrict__ b_ih1, const float* __restrict__ b_hh1,
    float* __restrict__ out, float* __restrict__ ws) {
  const int g = blockIdx.x;
  const int tid = threadIdx.x;
  const int lane = tid & 63;
  const int w = tid >> 6;

  unsigned* ws_u = (unsigned*)ws;

  __shared__ __align__(16) float h0s[CC];
  __shared__ __align__(16) float h1s[CC];
  __shared__ float st[36];
  __shared__ float cgi0[12], cbh0[12], cbh1[12], cbi1[12];
  __shared__ float red[NT];

  // ---------- P0: logits[t] = dot(w2, x[t]) ----------
  {
    const float* w2 = attn_w + CC;
#pragma unroll
    for (int s = 0; s < 2; ++s) {
      int t = 8 * g + 2 * w + s;
      const float* xr = x + (size_t)t * CC;
      float p = 0.f;
#pragma unroll
      for (int k = 0; k < 4; ++k) {
        f4 xa = *(const f4*)(xr + 256 * k + 4 * lane);
        f4 wa = *(const f4*)(w2 + 256 * k + 4 * lane);
        p += dot4(xa, wa);
      }
#pragma unroll
      for (int off = 32; off; off >>= 1) p += __shfl_xor(p, off, 64);
      if (lane == 0) astore(ws + WS_LOGITS + t, p);
    }
  }
  gbar(ws_u, 1);

  // ---------- P1: softmax over L, av columns [4g,4g+4) ----------
  {
    float myl[8];
#pragma unroll
    for (int s = 0; s < 8; ++s) myl[s] = aload(ws + WS_LOGITS + tid + 256 * s);
    float lm = myl[0];
#pragma unroll
    for (int s = 1; s < 8; ++s) lm = fmaxf(lm, myl[s]);
    red[tid] = lm;
    __syncthreads();
    for (int stp = 128; stp; stp >>= 1) {
      if (tid < stp) red[tid] = fmaxf(red[tid], red[tid + stp]);
      __syncthreads();
    }
    float m = red[0];
    __syncthreads();
    float myw[8];
    float ls = 0.f;
#pragma unroll
    for (int s = 0; s < 8; ++s) {
      myw[s] = __expf(myl[s] - m);
      ls += myw[s];
    }
    red[tid] = ls;
    __syncthreads();
    for (int stp = 128; stp; stp >>= 1) {
      if (tid < stp) red[tid] += red[tid + stp];
      __syncthreads();
    }
    float invZ = 1.0f / red[0];
    __syncthreads();
    float acc[4] = {0.f, 0.f, 0.f, 0.f};
#pragma unroll
    for (int s = 0; s < 8; ++s) {
      int t = tid + 256 * s;
      f4 xa = *(const f4*)(x + (size_t)t * CC + 4 * g);
      acc[0] = fmaf(myw[s], xa.x, acc[0]);
      acc[1] = fmaf(myw[s], xa.y, acc[1]);
      acc[2] = fmaf(myw[s], xa.z, acc[2]);
      acc[3] = fmaf(myw[s], xa.w, acc[3]);
    }
    for (int i = 0; i < 4; ++i) {
      red[tid] = acc[i];
      __syncthreads();
      for (int stp = 128; stp; stp >>= 1) {
        if (tid < stp) red[tid] += red[tid + stp];
        __syncthreads();
      }
      if (tid == 0) astore(ws + WS_AV + 4 * g + i, red[0] * invZ);
      __syncthreads();
    }
  }
  gbar(ws_u, 2);

  // ---------- P2: gi0 = W_ih0 . av + b_ih0 (this WG's 12 rows); biases ----------
#pragma unroll
  for (int i = 0; i < 4; ++i) h0s[4 * tid + i] = aload(ws + WS_AV + 4 * tid + i);
  __syncthreads();
  {
    f4 hc[4];
#pragma unroll
    for (int k = 0; k < 4; ++k) hc[k] = *(const f4*)&h0s[256 * k + 4 * lane];
#pragma unroll
    for (int jj = 0; jj < 3; ++jj) {
      int j = 3 * w + jj;
      int gate = j >> 2, e = j & 3;
      int row = gate * CC + 4 * g + e;
      const float* wr = w_ih0 + (size_t)row * CC;
      float p = 0.f;
#pragma unroll
      for (int k = 0; k < 4; ++k) p += dot4(*(const f4*)(wr + 256 * k + 4 * lane), hc[k]);
#pragma unroll
      for (int off = 32; off; off >>= 1) p += __shfl_xor(p, off, 64);
      if (lane == 0) cgi0[j] = p + b_ih0[row];
    }
  }
  if (tid < 12) {
    int gate = tid >> 2, e = tid & 3;
    int row = gate * CC + 4 * g + e;
    cbh0[tid] = b_hh0[row];
    cbh1[tid] = b_hh1[row];
    cbi1[tid] = b_ih1[row];
  }

  // ---------- weights -> VGPRs (9 rows/lane-slice; 36 f4 = 144 VGPRs) ----------
  f4 W[36];
#pragma unroll
  for (int i = 0; i < 3; ++i) {
    int j = 3 * w + i;
    int gate = j >> 2, e = j & 3;
    size_t row = (size_t)(gate * CC + 4 * g + e) << 10;
#pragma unroll
    for (int k = 0; k < 4; ++k) {
      W[i * 4 + k] = *(const f4*)(w_hh0 + row + 256 * k + 4 * lane);
      W[(3 + i) * 4 + k] = *(const f4*)(w_hh1 + row + 256 * k + 4 * lane);
      W[(6 + i) * 4 + k] = *(const f4*)(w_ih1 + row + 256 * k + 4 * lane);
    }
  }
#pragma unroll
  for (int i = 0; i < 4; ++i) {
    h0s[4 * tid + i] = 0.f;
    h1s[4 * tid + i] = 0.f;
  }
  __syncthreads();

  // ---------- skewed recurrence: tick tau computes h0[tau] and h1[tau-1] ----------
  const int e = lane & 3;
  const int eg = 4 * g + e;
  float h0last = 0.f;

  for (int tau = 0; tau <= LL; ++tau) {
    PIN9(0);
    PIN9(9);
    PIN9(18);
    PIN9(27);
    const int par = tau & 1;
    // (1) wave 0 polls the dense epoch array (coalesced, relaxed, L2-bypass)
    if (tau > 0 && w == 0) {
      const unsigned* epp = ws_u + WS_EP + 4 * lane;
      const unsigned ut = (unsigned)tau;
      int ok;
      do {
        u4 v = ld16u(epp);
        ok = (v.x >= ut) & (v.y >= ut) & (v.z >= ut) & (v.w >= ut);
      } while (!__all(ok));
    }
    __syncthreads();
    // (2) gather h0[tau-1], h1[tau-2] (dense, coalesced, bypass) -> LDS
    if (tau > 0) {
      const float* base = ws + (par ? WS_PAR1 : WS_PAR0);
      f4 a, b;
      ld16x2(base + 4 * tid, base + CC + 4 * tid, a, b);
      *(f4*)&h0s[4 * tid] = a;
      *(f4*)&h1s[4 * tid] = b;
    }
    __syncthreads();
    // (3) 9 dots from VGPR weights; butterfly reduce; st
    {
      f4 hc0[4], hc1[4];
#pragma unroll
      for (int k = 0; k < 4; ++k) {
        hc0[k] = *(const f4*)&h0s[256 * k + 4 * lane];
        hc1[k] = *(const f4*)&h1s[256 * k + 4 * lane];
      }
      float p[9];
#pragma unroll
      for (int i = 0; i < 3; ++i) {
        float pa = 0.f, pb = 0.f, pc = 0.f;
#pragma unroll
        for (int k = 0; k < 4; ++k) {
          pa += dot4(W[i * 4 + k], hc0[k]);
          pb += dot4(W[(3 + i) * 4 + k], hc1[k]);
          pc += dot4(W[(6 + i) * 4 + k], hc0[k]);
        }
        p[i] = pa;
        p[3 + i] = pb;
        p[6 + i] = pc;
      }
#pragma unroll
      for (int off = 32; off; off >>= 1) {
#pragma unroll
        for (int i = 0; i < 9; ++i) p[i] += __shfl_xor(p[i], off, 64);
      }
      if (lane == 0) {
#pragma unroll
        for (int i = 0; i < 3; ++i) {
          st[3 * w + i] = p[i];
          st[12 + 3 * w + i] = p[3 + i];
          st[24 + 3 * w + i] = p[6 + i];
        }
      }
    }
    __syncthreads();
    // (4) elementwise (all lanes; wave0 publishes + writes out)
    float h0prev = h0s[eg];
    float h1prev = h1s[eg];
    float r0 = sigm(cgi0[e] + st[e] + cbh0[e]);
    float z0 = sigm(cgi0[4 + e] + st[4 + e] + cbh0[4 + e]);
    float n0 = tanh_(cgi0[8 + e] + r0 * (st[8 + e] + cbh0[8 + e]));
    float h0new = (1.f - z0) * n0 + z0 * h0prev;

    float r1 = sigm(st[24 + e] + cbi1[e] + st[12 + e] + cbh1[e]);
    float z1 = sigm(st[28 + e] + cbi1[4 + e] + st[16 + e] + cbh1[4 + e]);
    float n1 = tanh_(st[32 + e] + cbi1[8 + e] + r1 * (st[20 + e] + cbh1[8 + e]));
    float h1new = (1.f - z1) * n1 + z1 * h1prev;

    if (w == 0) {
      f4 A, B;
      A.x = __shfl(h0new, 0, 64);
      A.y = __shfl(h0new, 1, 64);
      A.z = __shfl(h0new, 2, 64);
      A.w = __shfl(h0new, 3, 64);
      B.x = __shfl(h1new, 0, 64);
      B.y = __shfl(h1new, 1, 64);
      B.z = __shfl(h1new, 2, 64);
      B.w = __shfl(h1new, 3, 64);
      if (tau == 0) {
        B.x = 0.f;
        B.y = 0.f;
        B.z = 0.f;
        B.w = 0.f;
      }
      if (lane == 0 && tau < LL) {
        float* dst = ws + (par ? WS_PAR0 : WS_PAR1);  // parity (tau+1)&1
        st16(dst + 4 * g, A);
        st16(dst + CC + 4 * g, B);
        asm volatile("s_waitcnt vmcnt(0)" ::: "memory");
        __hip_atomic_store(ws_u + WS_EP + g, (unsigned)(tau + 1), __ATOMIC_RELAXED,
                           __HIP_MEMORY_SCOPE_AGENT);
      }
      if (lane < 4) {
        if (tau > 0) out[(size_t)(tau - 1) * CC + eg] = h1new;
        if (tau == LL) {
          out[(size_t)LL * CC + eg] = h0last;
          out[(size_t)LL * CC + CC + eg] = h1new;
        }
      }
    }
    if (tau == LL - 1) h0last = h0new;
  }
}

extern "C" void kernel_launch(void* const* d_in, const int* in_sizes, int n_in,
                              void* d_out, int out_size, void* d_ws, size_t ws_size,
                              hipStream_t stream) {
  const float* x = (const float*)d_in[0];
  const float* attn_w = (const float*)d_in[1];
  const float* w_ih0 = (const float*)d_in[3];
  const float* w_hh0 = (const float*)d_in[4];
  const float* b_ih0 = (const float*)d_in[5];
  const float* b_hh0 = (const float*)d_in[6];
  const float* w_ih1 = (const float*)d_in[7];
  const float* w_hh1 = (const float*)d_in[8];
  const float* b_ih1 = (const float*)d_in[9];
  const float* b_hh1 = (const float*)d_in[10];
  float* out = (float*)d_out;
  float* ws = (float*)d_ws;

  // zero gbar flags + release + tick epochs every call
  hipMemsetAsync(d_ws, 0, WS_MEMSET_BYTES, stream);

  void* args[] = {&x,     &attn_w, &w_ih0, &w_hh0, &b_ih0, &b_hh0,
                  &w_ih1, &w_hh1,  &b_ih1, &b_hh1, &out,   &ws};
  hipLaunchCooperativeKernel((void*)decoder_kernel, dim3(NWG), dim3(NT), args, 0,
                             stream);
}

// Round 5
// 7813.026 us; speedup vs baseline: 6.1314x; 1.2755x over previous
//
#include <hip/hip_runtime.h>
#include <math.h>

#define CC 1024
#define LL 2048
#define NWG 256
#define NT 256

typedef float f4 __attribute__((ext_vector_type(4)));
typedef unsigned u4 __attribute__((ext_vector_type(4)));

// ws word layout:
// [0..8191]      packet buffers: 2 parities x 4 arrays x 1024 words     [memset]
//                array w holds producer g's packet at w*1024 + 4*g:
//                (h0[4g+w], h1[4g+w], pad, tag)
// [8192..16383]  gbar arrival epochs (256 x 32 words, 128B lines)       [memset]
// [16384]        gbar release epoch                                     [memset]
// [16448..18495] logits[2048]
// [18496..19519] av[1024]
#define PKT_PAR 4096
#define PKT_ARR 1024
#define WS_FLAGS 8192
#define WS_REL 16384
#define WS_LOGITS 16448
#define WS_AV (WS_LOGITS + LL)
#define WS_MEMSET_BYTES ((WS_REL + 64) * 4)

__device__ __forceinline__ float aload(const float* p) {
  return __hip_atomic_load(p, __ATOMIC_RELAXED, __HIP_MEMORY_SCOPE_AGENT);
}
__device__ __forceinline__ void astore(float* p, float v) {
  __hip_atomic_store(p, v, __ATOMIC_RELAXED, __HIP_MEMORY_SCOPE_AGENT);
}
__device__ __forceinline__ float sigm(float x) { return 1.0f / (1.0f + __expf(-x)); }
__device__ __forceinline__ float tanh_(float x) { return 2.0f / (1.0f + __expf(-2.0f * x)) - 1.0f; }

__device__ __forceinline__ float dot4(f4 a, f4 b) {
  return fmaf(a.x, b.x, fmaf(a.y, b.y, fmaf(a.z, b.z, a.w * b.w)));
}

// 4 L2-bypass 16B loads issued together, single vmcnt wait (one RT per poll)
__device__ __forceinline__ void ld16u_x4(const unsigned* p0, const unsigned* p1,
                                         const unsigned* p2, const unsigned* p3,
                                         u4& a, u4& b, u4& c, u4& d) {
  asm volatile(
      "global_load_dwordx4 %0, %4, off sc0 sc1\n\t"
      "global_load_dwordx4 %1, %5, off sc0 sc1\n\t"
      "global_load_dwordx4 %2, %6, off sc0 sc1\n\t"
      "global_load_dwordx4 %3, %7, off sc0 sc1\n\t"
      "s_waitcnt vmcnt(0)"
      : "=v"(a), "=v"(b), "=v"(c), "=v"(d)
      : "v"(p0), "v"(p1), "v"(p2), "v"(p3)
      : "memory");
}
__device__ __forceinline__ void st16u(unsigned* p, u4 v) {
  asm volatile("global_store_dwordx4 %0, %1, off sc0 sc1" ::"v"(p), "v"(v) : "memory");
}

// prologue-only arrival-slot barrier (relaxed spins + one acquire)
__device__ __forceinline__ void gbar(unsigned* ws_u, unsigned epoch) {
  __syncthreads();
  if (blockIdx.x == 0) {
    const int i = threadIdx.x;
    if (i > 0 && i < NWG) {
      unsigned* slot = ws_u + WS_FLAGS + i * 32;
      while (__hip_atomic_load(slot, __ATOMIC_RELAXED, __HIP_MEMORY_SCOPE_AGENT) < epoch) {
      }
      (void)__hip_atomic_load(slot, __ATOMIC_ACQUIRE, __HIP_MEMORY_SCOPE_AGENT);
    }
    __syncthreads();
    if (i == 0)
      __hip_atomic_store(ws_u + WS_REL, epoch, __ATOMIC_RELEASE, __HIP_MEMORY_SCOPE_AGENT);
    __syncthreads();
  } else {
    if (threadIdx.x == 0) {
      __hip_atomic_store(ws_u + WS_FLAGS + blockIdx.x * 32, epoch, __ATOMIC_RELEASE,
                         __HIP_MEMORY_SCOPE_AGENT);
      unsigned* rel = ws_u + WS_REL;
      while (__hip_atomic_load(rel, __ATOMIC_RELAXED, __HIP_MEMORY_SCOPE_AGENT) < epoch) {
      }
      (void)__hip_atomic_load(rel, __ATOMIC_ACQUIRE, __HIP_MEMORY_SCOPE_AGENT);
    }
    __syncthreads();
  }
}

#define PIN9(b)                                                                       \
  asm volatile("" : "+v"(W[b + 0]), "+v"(W[b + 1]), "+v"(W[b + 2]), "+v"(W[b + 3]),   \
                    "+v"(W[b + 4]), "+v"(W[b + 5]), "+v"(W[b + 6]), "+v"(W[b + 7]),   \
                    "+v"(W[b + 8]))

__global__ __launch_bounds__(NT, 1) void decoder_kernel(
    const float* __restrict__ x, const float* __restrict__ attn_w,
    const float* __restrict__ w_ih0, const float* __restrict__ w_hh0,
    const float* __restrict__ b_ih0, const float* __restrict__ b_hh0,
    const float* __restrict__ w_ih1, const float* __restrict__ w_hh1,
    const float* __restrict__ b_ih1, const float* __restrict__ b_hh1,
    float* __restrict__ out, float* __restrict__ ws) {
  const int g = blockIdx.x;
  const int tid = threadIdx.x;
  const int lane = tid & 63;
  const int w = tid >> 6;

  unsigned* ws_u = (unsigned*)ws;

  __shared__ __align__(16) float h0s[CC];
  __shared__ __align__(16) float h1s[CC];
  __shared__ float cgi0[12], cbh0[12], cbh1[12], cbi1[12];
  __shared__ float red[NT];

  // ---------- P0: logits[t] = dot(w2, x[t]) ----------
  {
    const float* w2 = attn_w + CC;
#pragma unroll
    for (int s = 0; s < 2; ++s) {
      int t = 8 * g + 2 * w + s;
      const float* xr = x + (size_t)t * CC;
      float p = 0.f;
#pragma unroll
      for (int k = 0; k < 4; ++k) {
        f4 xa = *(const f4*)(xr + 256 * k + 4 * lane);
        f4 wa = *(const f4*)(w2 + 256 * k + 4 * lane);
        p += dot4(xa, wa);
      }
#pragma unroll
      for (int off = 32; off; off >>= 1) p += __shfl_xor(p, off, 64);
      if (lane == 0) astore(ws + WS_LOGITS + t, p);
    }
  }
  gbar(ws_u, 1);

  // ---------- P1: softmax over L, av columns [4g,4g+4) ----------
  {
    float myl[8];
#pragma unroll
    for (int s = 0; s < 8; ++s) myl[s] = aload(ws + WS_LOGITS + tid + 256 * s);
    float lm = myl[0];
#pragma unroll
    for (int s = 1; s < 8; ++s) lm = fmaxf(lm, myl[s]);
    red[tid] = lm;
    __syncthreads();
    for (int stp = 128; stp; stp >>= 1) {
      if (tid < stp) red[tid] = fmaxf(red[tid], red[tid + stp]);
      __syncthreads();
    }
    float m = red[0];
    __syncthreads();
    float myw[8];
    float ls = 0.f;
#pragma unroll
    for (int s = 0; s < 8; ++s) {
      myw[s] = __expf(myl[s] - m);
      ls += myw[s];
    }
    red[tid] = ls;
    __syncthreads();
    for (int stp = 128; stp; stp >>= 1) {
      if (tid < stp) red[tid] += red[tid + stp];
      __syncthreads();
    }
    float invZ = 1.0f / red[0];
    __syncthreads();
    float acc[4] = {0.f, 0.f, 0.f, 0.f};
#pragma unroll
    for (int s = 0; s < 8; ++s) {
      int t = tid + 256 * s;
      f4 xa = *(const f4*)(x + (size_t)t * CC + 4 * g);
      acc[0] = fmaf(myw[s], xa.x, acc[0]);
      acc[1] = fmaf(myw[s], xa.y, acc[1]);
      acc[2] = fmaf(myw[s], xa.z, acc[2]);
      acc[3] = fmaf(myw[s], xa.w, acc[3]);
    }
    for (int i = 0; i < 4; ++i) {
      red[tid] = acc[i];
      __syncthreads();
      for (int stp = 128; stp; stp >>= 1) {
        if (tid < stp) red[tid] += red[tid + stp];
        __syncthreads();
      }
      if (tid == 0) astore(ws + WS_AV + 4 * g + i, red[0] * invZ);
      __syncthreads();
    }
  }
  gbar(ws_u, 2);

  // ---------- P2: gi0 = W_ih0 . av + b_ih0 (this WG's 12 rows); biases ----------
#pragma unroll
  for (int i = 0; i < 4; ++i) h0s[4 * tid + i] = aload(ws + WS_AV + 4 * tid + i);
  __syncthreads();
  {
    f4 hc[4];
#pragma unroll
    for (int k = 0; k < 4; ++k) hc[k] = *(const f4*)&h0s[256 * k + 4 * lane];
#pragma unroll
    for (int jj = 0; jj < 3; ++jj) {
      int j = 3 * w + jj;
      int gate = j >> 2, e = j & 3;
      int row = gate * CC + 4 * g + e;
      const float* wr = w_ih0 + (size_t)row * CC;
      float p = 0.f;
#pragma unroll
      for (int k = 0; k < 4; ++k) p += dot4(*(const f4*)(wr + 256 * k + 4 * lane), hc[k]);
#pragma unroll
      for (int off = 32; off; off >>= 1) p += __shfl_xor(p, off, 64);
      if (lane == 0) cgi0[j] = p + b_ih0[row];
    }
  }
  if (tid < 12) {
    int gate = tid >> 2, e = tid & 3;
    int row = gate * CC + 4 * g + e;
    cbh0[tid] = b_hh0[row];
    cbh1[tid] = b_hh1[row];
    cbi1[tid] = b_ih1[row];
  }

  // ---------- weights -> VGPRs: wave w owns all 3 gate rows of element 4g+w ----------
  // W[(mat*3+G)*4+k]: mat 0=W_hh0, 1=W_hh1, 2=W_ih1; row = G*CC + 4g + w
  f4 W[36];
#pragma unroll
  for (int G = 0; G < 3; ++G) {
    size_t row = (size_t)(G * CC + 4 * g + w) << 10;
#pragma unroll
    for (int k = 0; k < 4; ++k) {
      W[(0 * 3 + G) * 4 + k] = *(const f4*)(w_hh0 + row + 256 * k + 4 * lane);
      W[(1 * 3 + G) * 4 + k] = *(const f4*)(w_hh1 + row + 256 * k + 4 * lane);
      W[(2 * 3 + G) * 4 + k] = *(const f4*)(w_ih1 + row + 256 * k + 4 * lane);
    }
  }
#pragma unroll
  for (int i = 0; i < 4; ++i) {
    h0s[4 * tid + i] = 0.f;
    h1s[4 * tid + i] = 0.f;
  }
  __syncthreads();

  // ---------- skewed recurrence: tick tau computes h0[tau] and h1[tau-1] ----------
  float h0last = 0.f;
  unsigned* pkt0 = ws_u;            // parity 0
  unsigned* pkt1 = ws_u + PKT_PAR;  // parity 1

  for (int tau = 0; tau <= LL; ++tau) {
    PIN9(0);
    PIN9(9);
    PIN9(18);
    PIN9(27);
    // (1) poll producer tid's 4 self-validating packets; tag match => data valid
    if (tau > 0) {
      const unsigned ut = (unsigned)tau;
      unsigned* base = (tau & 1) ? pkt1 : pkt0;
      const unsigned* pA = base + 0 * PKT_ARR + 4 * tid;
      const unsigned* pB = base + 1 * PKT_ARR + 4 * tid;
      const unsigned* pC = base + 2 * PKT_ARR + 4 * tid;
      const unsigned* pD = base + 3 * PKT_ARR + 4 * tid;
      u4 a, b, c, d;
      do {
        ld16u_x4(pA, pB, pC, pD, a, b, c, d);
      } while (a.w != ut || b.w != ut || c.w != ut || d.w != ut);
      f4 v0, v1;
      v0.x = __uint_as_float(a.x);
      v0.y = __uint_as_float(b.x);
      v0.z = __uint_as_float(c.x);
      v0.w = __uint_as_float(d.x);
      v1.x = __uint_as_float(a.y);
      v1.y = __uint_as_float(b.y);
      v1.z = __uint_as_float(c.y);
      v1.w = __uint_as_float(d.y);
      *(f4*)&h0s[4 * tid] = v0;
      *(f4*)&h1s[4 * tid] = v1;
    }
    __syncthreads();
    // (2) wave-local: 9 dots (3 gates x 3 matrices for element 4g+w)
    f4 hc0[4], hc1[4];
#pragma unroll
    for (int k = 0; k < 4; ++k) {
      hc0[k] = *(const f4*)&h0s[256 * k + 4 * lane];
      hc1[k] = *(const f4*)&h1s[256 * k + 4 * lane];
    }
    float h0prev = h0s[4 * g + w];
    float h1prev = h1s[4 * g + w];
    float p[9];
#pragma unroll
    for (int G = 0; G < 3; ++G) {
      float pa = 0.f, pb = 0.f, pc = 0.f;
#pragma unroll
      for (int k = 0; k < 4; ++k) {
        pa += dot4(W[(0 * 3 + G) * 4 + k], hc0[k]);
        pb += dot4(W[(1 * 3 + G) * 4 + k], hc1[k]);
        pc += dot4(W[(2 * 3 + G) * 4 + k], hc0[k]);
      }
      p[G] = pa;
      p[3 + G] = pb;
      p[6 + G] = pc;
    }
#pragma unroll
    for (int off = 32; off; off >>= 1) {
#pragma unroll
      for (int i = 0; i < 9; ++i) p[i] += __shfl_xor(p[i], off, 64);
    }
    // (3) elementwise update, wave-local (element e = w)
    float r0 = sigm(cgi0[w] + p[0] + cbh0[w]);
    float z0 = sigm(cgi0[4 + w] + p[1] + cbh0[4 + w]);
    float n0 = tanh_(cgi0[8 + w] + r0 * (p[2] + cbh0[8 + w]));
    float h0new = (1.f - z0) * n0 + z0 * h0prev;

    float r1 = sigm(p[6] + cbi1[w] + p[3] + cbh1[w]);
    float z1 = sigm(p[7] + cbi1[4 + w] + p[4] + cbh1[4 + w]);
    float n1 = tanh_(p[8] + cbi1[8 + w] + r1 * (p[5] + cbh1[8 + w]));
    float h1new = (1.f - z1) * n1 + z1 * h1prev;

    // (4) publish one self-validating packet per wave; write out
    if (lane == 0) {
      if (tau < LL) {
        u4 pk;
        pk.x = __float_as_uint(h0new);
        pk.y = __float_as_uint((tau > 0) ? h1new : 0.f);
        pk.z = 0u;
        pk.w = (unsigned)(tau + 1);
        unsigned* dst = (((tau + 1) & 1) ? pkt1 : pkt0) + w * PKT_ARR + 4 * g;
        st16u(dst, pk);
      }
      if (tau > 0) out[(size_t)(tau - 1) * CC + 4 * g + w] = h1new;
      if (tau == LL) {
        out[(size_t)LL * CC + 4 * g + w] = h0last;
        out[(size_t)LL * CC + CC + 4 * g + w] = h1new;
      }
    }
    if (tau == LL - 1) h0last = h0new;
    __syncthreads();  // protect h0s/h1s from next tick's overwrite
  }
}

extern "C" void kernel_launch(void* const* d_in, const int* in_sizes, int n_in,
                              void* d_out, int out_size, void* d_ws, size_t ws_size,
                              hipStream_t stream) {
  const float* x = (const float*)d_in[0];
  const float* attn_w = (const float*)d_in[1];
  const float* w_ih0 = (const float*)d_in[3];
  const float* w_hh0 = (const float*)d_in[4];
  const float* b_ih0 = (const float*)d_in[5];
  const float* b_hh0 = (const float*)d_in[6];
  const float* w_ih1 = (const float*)d_in[7];
  const float* w_hh1 = (const float*)d_in[8];
  const float* b_ih1 = (const float*)d_in[9];
  const float* b_hh1 = (const float*)d_in[10];
  float* out = (float*)d_out;
  float* ws = (float*)d_ws;

  // zero packet tags + gbar flags every call (prevents cross-replay ABA)
  hipMemsetAsync(d_ws, 0, WS_MEMSET_BYTES, stream);

  void* args[] = {&x,     &attn_w, &w_ih0, &w_hh0, &b_ih0, &b_hh0,
                  &w_ih1, &w_hh1,  &b_ih1, &b_hh1, &out,   &ws};
  hipLaunchCooperativeKernel((void*)decoder_kernel, dim3(NWG), dim3(NT), args, 0,
                             stream);
}